// Round 2
// baseline (306.173 us; speedup 1.0000x reference)
//
#include <hip/hip_runtime.h>
#include <math.h>

// Problem dims (fixed by setup_inputs): B=1024, D=256, H=1024
#define Bsz 1024
#define Dsz 256
#define Hsz 1024

// ---------------------------------------------------------------------------
// Shared tile helpers: 64x64 output tile, BK=16, 256 threads, 4x4 per thread.
// As is stored K-major (As[kk][m]) so the inner loop does float4 reads.
// ---------------------------------------------------------------------------

// A row-major [M,K]; load tile rows row0..+64, k0..+16 into As[kk][m] (transposed).
// If SQ, transform each element a -> 1 - a*a (d = 1 - h^2 on the fly).
template <bool SQ>
__device__ __forceinline__ void load_tileA_rm(float As[16][64], const float* __restrict__ A,
                                              int lda, int row0, int k0, int tid) {
  const int m = tid >> 2;           // 0..63
  const int q = (tid & 3) << 2;     // 0,4,8,12
  const float4 v = *reinterpret_cast<const float4*>(&A[(size_t)(row0 + m) * lda + k0 + q]);
  float a0 = v.x, a1 = v.y, a2 = v.z, a3 = v.w;
  if (SQ) {
    a0 = 1.0f - a0 * a0; a1 = 1.0f - a1 * a1;
    a2 = 1.0f - a2 * a2; a3 = 1.0f - a3 * a3;
  }
  As[q + 0][m] = a0; As[q + 1][m] = a1; As[q + 2][m] = a2; As[q + 3][m] = a3;
}

// B row-major [K,N]; load rows k0..+16, cols col0..+64 into Bs[kk][n].
__device__ __forceinline__ void load_tileB_rm(float Bs[16][64], const float* __restrict__ Bm,
                                              int ldb, int k0, int col0, int tid) {
  const int kk = tid >> 4;          // 0..15
  const int n = (tid & 15) << 2;    // 0..60
  *reinterpret_cast<float4*>(&Bs[kk][n]) =
      *reinterpret_cast<const float4*>(&Bm[(size_t)(k0 + kk) * ldb + col0 + n]);
}

// B = Wᵀ where W is row-major [N_total, K_total]; element [k][n] = W[n][k].
// Load W rows (coalesced 16B per row) and scatter into Bs[kk][n].
__device__ __forceinline__ void load_tileB_tr(float Bs[16][64], const float* __restrict__ W,
                                              int ldw, int k0, int col0, int tid) {
  const int n = tid >> 2;           // 0..63
  const int q = (tid & 3) << 2;     // 0,4,8,12
  const float4 v = *reinterpret_cast<const float4*>(&W[(size_t)(col0 + n) * ldw + k0 + q]);
  Bs[q + 0][n] = v.x; Bs[q + 1][n] = v.y; Bs[q + 2][n] = v.z; Bs[q + 3][n] = v.w;
}

__device__ __forceinline__ void fma_tile(const float As[16][64], const float Bs[16][64],
                                         int tx, int ty, float c[4][4]) {
#pragma unroll
  for (int kk = 0; kk < 16; ++kk) {
    const float4 a4 = *reinterpret_cast<const float4*>(&As[kk][ty << 2]);
    const float4 b4 = *reinterpret_cast<const float4*>(&Bs[kk][tx << 2]);
    const float av[4] = {a4.x, a4.y, a4.z, a4.w};
    const float bv[4] = {b4.x, b4.y, b4.z, b4.w};
#pragma unroll
    for (int i = 0; i < 4; ++i)
#pragma unroll
      for (int j = 0; j < 4; ++j) c[i][j] += av[i] * bv[j];
  }
}

// ---------------------------------------------------------------------------
// Kernel 1: H1 = tanh(x @ W1 + b1 + ts*tW)   [B,H], K=D=256
// ---------------------------------------------------------------------------
__global__ __launch_bounds__(256) void k1_layer1(const float* __restrict__ x,
                                                 const float* __restrict__ W1,
                                                 const float* __restrict__ b1,
                                                 const float* __restrict__ tW,
                                                 const float* __restrict__ t,
                                                 float* __restrict__ H1) {
  __shared__ float As[16][64];
  __shared__ float Bs[16][64];
  const int tid = threadIdx.x;
  const int tx = tid & 15, ty = tid >> 4;
  const int row0 = blockIdx.y * 64, col0 = blockIdx.x * 64;
  float c[4][4] = {};
  for (int k0 = 0; k0 < Dsz; k0 += 16) {
    load_tileA_rm<false>(As, x, Dsz, row0, k0, tid);
    load_tileB_rm(Bs, W1, Hsz, k0, col0, tid);
    __syncthreads();
    fma_tile(As, Bs, tx, ty, c);
    __syncthreads();
  }
  const float ts = t[0];
  const int col = col0 + (tx << 2);
  const float4 bb = *reinterpret_cast<const float4*>(&b1[col]);
  const float4 tw = *reinterpret_cast<const float4*>(&tW[col]);
  const float add0 = bb.x + ts * tw.x, add1 = bb.y + ts * tw.y;
  const float add2 = bb.z + ts * tw.z, add3 = bb.w + ts * tw.w;
#pragma unroll
  for (int i = 0; i < 4; ++i) {
    const int row = row0 + (ty << 2) + i;
    float4 o;
    o.x = tanhf(c[i][0] + add0);
    o.y = tanhf(c[i][1] + add1);
    o.z = tanhf(c[i][2] + add2);
    o.w = tanhf(c[i][3] + add3);
    *reinterpret_cast<float4*>(&H1[(size_t)row * Hsz + col]) = o;
  }
}

// ---------------------------------------------------------------------------
// Kernel 2: Amat[i,j] = (Σ_d W1[d,i]·W3[j,d]) * W2[i,j]   [H,H], K=D=256
//   A-operand = W1ᵀ (element [i,d] = W1[d,i]) -> loads like a B tile from W1
//   B-operand = W3ᵀ (element [d,j] = W3[j,d]) -> transposed load from W3 rows
// ---------------------------------------------------------------------------
__global__ __launch_bounds__(256) void k2_amat(const float* __restrict__ W1,
                                               const float* __restrict__ W3,
                                               const float* __restrict__ W2,
                                               float* __restrict__ Amat) {
  __shared__ float As[16][64];
  __shared__ float Bs[16][64];
  const int tid = threadIdx.x;
  const int tx = tid & 15, ty = tid >> 4;
  const int row0 = blockIdx.y * 64, col0 = blockIdx.x * 64;
  float c[4][4] = {};
  for (int k0 = 0; k0 < Dsz; k0 += 16) {
    load_tileB_rm(As, W1, Hsz, k0, row0, tid);  // As[kk][i] = W1[k0+kk][row0+i]
    load_tileB_tr(Bs, W3, Dsz, k0, col0, tid);  // Bs[kk][j] = W3[col0+j][k0+kk]
    __syncthreads();
    fma_tile(As, Bs, tx, ty, c);
    __syncthreads();
  }
  const int col = col0 + (tx << 2);
#pragma unroll
  for (int i = 0; i < 4; ++i) {
    const int row = row0 + (ty << 2) + i;
    const float4 w2 = *reinterpret_cast<const float4*>(&W2[(size_t)row * Hsz + col]);
    float4 o;
    o.x = c[i][0] * w2.x; o.y = c[i][1] * w2.y;
    o.z = c[i][2] * w2.z; o.w = c[i][3] * w2.w;
    *reinterpret_cast<float4*>(&Amat[(size_t)row * Hsz + col]) = o;
  }
}

// ---------------------------------------------------------------------------
// Kernel 3: H2 = tanh(H1 @ W2 + b2)   [B,H], K=H=1024
// ---------------------------------------------------------------------------
__global__ __launch_bounds__(256) void k3_layer2(const float* __restrict__ H1,
                                                 const float* __restrict__ W2,
                                                 const float* __restrict__ b2,
                                                 float* __restrict__ H2) {
  __shared__ float As[16][64];
  __shared__ float Bs[16][64];
  const int tid = threadIdx.x;
  const int tx = tid & 15, ty = tid >> 4;
  const int row0 = blockIdx.y * 64, col0 = blockIdx.x * 64;
  float c[4][4] = {};
  for (int k0 = 0; k0 < Hsz; k0 += 16) {
    load_tileA_rm<false>(As, H1, Hsz, row0, k0, tid);
    load_tileB_rm(Bs, W2, Hsz, k0, col0, tid);
    __syncthreads();
    fma_tile(As, Bs, tx, ty, c);
    __syncthreads();
  }
  const int col = col0 + (tx << 2);
  const float4 bb = *reinterpret_cast<const float4*>(&b2[col]);
#pragma unroll
  for (int i = 0; i < 4; ++i) {
    const int row = row0 + (ty << 2) + i;
    float4 o;
    o.x = tanhf(c[i][0] + bb.x);
    o.y = tanhf(c[i][1] + bb.y);
    o.z = tanhf(c[i][2] + bb.z);
    o.w = tanhf(c[i][3] + bb.w);
    *reinterpret_cast<float4*>(&H2[(size_t)row * Hsz + col]) = o;
  }
}

// ---------------------------------------------------------------------------
// Kernel 4: dx = H2 @ W3 + b3   [B,D], K=H=1024
// ---------------------------------------------------------------------------
__global__ __launch_bounds__(256) void k4_dx(const float* __restrict__ H2,
                                             const float* __restrict__ W3,
                                             const float* __restrict__ b3,
                                             float* __restrict__ dx) {
  __shared__ float As[16][64];
  __shared__ float Bs[16][64];
  const int tid = threadIdx.x;
  const int tx = tid & 15, ty = tid >> 4;
  const int row0 = blockIdx.y * 64, col0 = blockIdx.x * 64;
  float c[4][4] = {};
  for (int k0 = 0; k0 < Hsz; k0 += 16) {
    load_tileA_rm<false>(As, H2, Hsz, row0, k0, tid);
    load_tileB_rm(Bs, W3, Dsz, k0, col0, tid);
    __syncthreads();
    fma_tile(As, Bs, tx, ty, c);
    __syncthreads();
  }
  const int col = col0 + (tx << 2);
  const float4 bb = *reinterpret_cast<const float4*>(&b3[col]);
#pragma unroll
  for (int i = 0; i < 4; ++i) {
    const int row = row0 + (ty << 2) + i;
    float4 o;
    o.x = c[i][0] + bb.x; o.y = c[i][1] + bb.y;
    o.z = c[i][2] + bb.z; o.w = c[i][3] + bb.w;
    *reinterpret_cast<float4*>(&dx[(size_t)row * Dsz + col]) = o;
  }
}

// ---------------------------------------------------------------------------
// Kernel 5: U = (1 - H1^2) @ Amat; ldj[b] += Σ_j U[b,j] * (1 - H2[b,j]^2)
//   per-block: 64x64 tile of U, masked column-reduce, atomicAdd per row.
// ---------------------------------------------------------------------------
__global__ __launch_bounds__(256) void k5_trace(const float* __restrict__ H1,
                                                const float* __restrict__ Amat,
                                                const float* __restrict__ H2,
                                                float* __restrict__ ldj) {
  __shared__ float As[16][64];
  __shared__ float Bs[16][64];
  __shared__ float sred[64][17];
  const int tid = threadIdx.x;
  const int tx = tid & 15, ty = tid >> 4;
  const int row0 = blockIdx.y * 64, col0 = blockIdx.x * 64;
  float c[4][4] = {};
  for (int k0 = 0; k0 < Hsz; k0 += 16) {
    load_tileA_rm<true>(As, H1, Hsz, row0, k0, tid);  // d1 = 1 - h1^2 on the fly
    load_tileB_rm(Bs, Amat, Hsz, k0, col0, tid);
    __syncthreads();
    fma_tile(As, Bs, tx, ty, c);
    __syncthreads();
  }
  const int col = col0 + (tx << 2);
#pragma unroll
  for (int i = 0; i < 4; ++i) {
    const int row = row0 + (ty << 2) + i;
    const float4 h2 = *reinterpret_cast<const float4*>(&H2[(size_t)row * Hsz + col]);
    float s = c[i][0] * (1.0f - h2.x * h2.x)
            + c[i][1] * (1.0f - h2.y * h2.y)
            + c[i][2] * (1.0f - h2.z * h2.z)
            + c[i][3] * (1.0f - h2.w * h2.w);
    sred[(ty << 2) + i][tx] = s;
  }
  __syncthreads();
  if (tid < 64) {
    float s = 0.0f;
#pragma unroll
    for (int u = 0; u < 16; ++u) s += sred[tid][u];
    atomicAdd(&ldj[row0 + tid], s);
  }
}

// ---------------------------------------------------------------------------
// Launch
// ---------------------------------------------------------------------------
extern "C" void kernel_launch(void* const* d_in, const int* in_sizes, int n_in,
                              void* d_out, int out_size, void* d_ws, size_t ws_size,
                              hipStream_t stream) {
  const float* x  = (const float*)d_in[0];
  const float* t  = (const float*)d_in[1];
  // d_in[2] = ldj (zeros, unused), d_in[3] = reg_term (zeros, unused)
  const float* W1 = (const float*)d_in[4];
  const float* b1 = (const float*)d_in[5];
  const float* tW = (const float*)d_in[6];
  const float* W2 = (const float*)d_in[7];
  const float* b2 = (const float*)d_in[8];
  const float* W3 = (const float*)d_in[9];
  const float* b3 = (const float*)d_in[10];

  float* out = (float*)d_out;
  float* dx  = out;                          // [B,D] = 262144
  float* ldj = out + (size_t)Bsz * Dsz;      // [B]   = 1024, then reg [B]

  float* ws   = (float*)d_ws;
  float* H1   = ws;                          // [B,H] 1M floats
  float* H2   = ws + (size_t)Bsz * Hsz;      // [B,H] 1M floats
  float* Amat = ws + 2 * (size_t)Bsz * Hsz;  // [H,H] 1M floats

  // ldj accumulates via atomics; reg_out must be exactly zero.
  hipMemsetAsync(ldj, 0, 2 * Bsz * sizeof(float), stream);

  const dim3 blk(256);
  k2_amat  <<<dim3(Hsz / 64, Hsz / 64), blk, 0, stream>>>(W1, W3, W2, Amat);
  k1_layer1<<<dim3(Hsz / 64, Bsz / 64), blk, 0, stream>>>(x, W1, b1, tW, t, H1);
  k3_layer2<<<dim3(Hsz / 64, Bsz / 64), blk, 0, stream>>>(H1, W2, b2, H2);
  k4_dx    <<<dim3(Dsz / 64, Bsz / 64), blk, 0, stream>>>(H2, W3, b3, dx);
  k5_trace <<<dim3(Hsz / 64, Bsz / 64), blk, 0, stream>>>(H1, Amat, H2, ldj);
}

// Round 4
// 150.231 us; speedup vs baseline: 2.0380x; 2.0380x over previous
//
#include <hip/hip_runtime.h>
#include <math.h>

// Problem dims (fixed by setup_inputs): B=1024, D=256, H=1024
#define Bsz 1024
#define Dsz 256
#define Hsz 1024

typedef unsigned short u16;
typedef __bf16 bf16x8 __attribute__((ext_vector_type(8)));
typedef float  f32x4  __attribute__((ext_vector_type(4)));

__device__ __forceinline__ float bf2f(u16 u) {
  unsigned v = ((unsigned)u) << 16;
  return __builtin_bit_cast(float, v);
}
__device__ __forceinline__ u16 f2bf(float f) {
  unsigned u = __builtin_bit_cast(unsigned, f);
  u += 0x7FFFu + ((u >> 16) & 1u);  // round-to-nearest-even
  return (u16)(u >> 16);
}

// ---------------------------------------------------------------------------
// conv_cast: f32 -> bf16, elementwise (n4 = n/4 float4 chunks)
// ---------------------------------------------------------------------------
__global__ __launch_bounds__(256) void conv_cast(const float* __restrict__ in,
                                                 u16* __restrict__ out, int n4) {
  const int i = blockIdx.x * 256 + threadIdx.x;
  if (i < n4) {
    const float4 v = reinterpret_cast<const float4*>(in)[i];
    ushort4 o;
    o.x = f2bf(v.x); o.y = f2bf(v.y); o.z = f2bf(v.z); o.w = f2bf(v.w);
    *reinterpret_cast<ushort4*>(&out[(size_t)i * 4]) = o;
  }
}

// ---------------------------------------------------------------------------
// conv_tr: f32 [R][C] -> bf16 [C][R] (transpose+cast), 64x64 tiles via LDS
// grid = (C/64, R/64)
// ---------------------------------------------------------------------------
__global__ __launch_bounds__(256) void conv_tr(const float* __restrict__ in,
                                               u16* __restrict__ out, int R, int C) {
  __shared__ float tl[64][65];
  const int t = threadIdx.x;
  const int c0 = blockIdx.x * 64, r0 = blockIdx.y * 64;
#pragma unroll
  for (int p = 0; p < 4; ++p) {
    const int r = p * 16 + (t >> 4);
    const int c = (t & 15) * 4;
    const float4 v = *reinterpret_cast<const float4*>(&in[(size_t)(r0 + r) * C + c0 + c]);
    tl[r][c] = v.x; tl[r][c + 1] = v.y; tl[r][c + 2] = v.z; tl[r][c + 3] = v.w;
  }
  __syncthreads();
#pragma unroll
  for (int p = 0; p < 4; ++p) {
    const int a = p * 16 + (t >> 4);   // out row (= in col)
    const int b4 = (t & 15) * 4;       // out col (= in row)
    ushort4 o;
    o.x = f2bf(tl[b4 + 0][a]); o.y = f2bf(tl[b4 + 1][a]);
    o.z = f2bf(tl[b4 + 2][a]); o.w = f2bf(tl[b4 + 3][a]);
    *reinterpret_cast<ushort4*>(&out[(size_t)(c0 + a) * R + r0 + b4]) = o;
  }
}

// ---------------------------------------------------------------------------
// MFMA GEMM: C[64x64 tile] = A[M][K] * Bt[N][K]^T, bf16 inputs, f32 accum.
// 256 threads = 4 waves in 2x2; each wave a 32x32 quadrant (2x2 16x16 frags).
// BK=64, reg-prefetch of next tile. LDS rows padded to 72 bf16 (<=2-way bank).
// Epilogues select the 5 fused ops. SQA: transform A elems h -> 1-h*h while
// staging (gives d1 from H1b without a separate buffer).
// ---------------------------------------------------------------------------
enum { EPI_H1 = 0, EPI_AMAT = 1, EPI_H2 = 2, EPI_DX = 3, EPI_TRACE = 4 };

template <int EPI, bool SQA>
__global__ __launch_bounds__(256) void gemm_mfma(
    const u16* __restrict__ A,    // [M][K] bf16
    const u16* __restrict__ Bt,   // [N][K] bf16
    int K, int ldo,
    float* __restrict__ fout,     // dx (DX) / ldj (TRACE)
    u16* __restrict__ bout,       // H1b / AmatT / H2b
    const u16* __restrict__ aux,  // W2bT (AMAT) / H2b (TRACE)
    const float* __restrict__ v1, // b1 / b2 / b3
    const float* __restrict__ v2, // tW
    const float* __restrict__ tptr) {
  constexpr int LS = 72;  // LDS row stride in bf16 elems (144B: 2-way max)
  __shared__ u16 As[64 * LS];
  __shared__ u16 Bs[64 * LS];
  __shared__ float sred[64][33];

  const int t = threadIdx.x;
  const int lane = t & 63, wid = t >> 6;
  const int row0 = blockIdx.y * 64, col0 = blockIdx.x * 64;

  // staging: thread t covers row sm, 16B chunk sq (+0 and +32 elems)
  const int sm = t >> 2, sq = t & 3;
  const size_t a_base = (size_t)(row0 + sm) * K + sq * 8;
  const size_t b_base = (size_t)(col0 + sm) * K + sq * 8;

  uint4 ar[2], br[2];
  auto load_regs = [&](int k0) {
    ar[0] = *reinterpret_cast<const uint4*>(&A[a_base + k0]);
    ar[1] = *reinterpret_cast<const uint4*>(&A[a_base + k0 + 32]);
    br[0] = *reinterpret_cast<const uint4*>(&Bt[b_base + k0]);
    br[1] = *reinterpret_cast<const uint4*>(&Bt[b_base + k0 + 32]);
  };
  auto sq_tr = [&](uint4 v) -> uint4 {
    u16* p = reinterpret_cast<u16*>(&v);
    uint4 o; u16* po = reinterpret_cast<u16*>(&o);
#pragma unroll
    for (int i = 0; i < 8; ++i) { const float h = bf2f(p[i]); po[i] = f2bf(1.0f - h * h); }
    return o;
  };
  auto store_lds = [&]() {
    const int ab = sm * LS + sq * 8;
#pragma unroll
    for (int c = 0; c < 2; ++c) {
      const uint4 av = SQA ? sq_tr(ar[c]) : ar[c];
      *reinterpret_cast<uint4*>(&As[ab + c * 32]) = av;
      *reinterpret_cast<uint4*>(&Bs[ab + c * 32]) = br[c];
    }
  };

  f32x4 acc[2][2] = {};
  const int mo = (wid >> 1) * 32, no = (wid & 1) * 32;
  const int fr = lane & 15, fg = lane >> 4;

  const int NK = K >> 6;
  load_regs(0);
  for (int it = 0; it < NK; ++it) {
    __syncthreads();          // previous compute done; LDS free
    store_lds();
    if (it + 1 < NK) load_regs((it + 1) << 6);
    __syncthreads();          // tile visible
#pragma unroll
    for (int ks = 0; ks < 64; ks += 32) {
      union { uint4 u; bf16x8 b; } cv;
      cv.u = *reinterpret_cast<const uint4*>(&As[(mo + fr) * LS + ks + fg * 8]);
      const bf16x8 a0 = cv.b;
      cv.u = *reinterpret_cast<const uint4*>(&As[(mo + 16 + fr) * LS + ks + fg * 8]);
      const bf16x8 a1 = cv.b;
      cv.u = *reinterpret_cast<const uint4*>(&Bs[(no + fr) * LS + ks + fg * 8]);
      const bf16x8 b0 = cv.b;
      cv.u = *reinterpret_cast<const uint4*>(&Bs[(no + 16 + fr) * LS + ks + fg * 8]);
      const bf16x8 b1 = cv.b;
      acc[0][0] = __builtin_amdgcn_mfma_f32_16x16x32_bf16(a0, b0, acc[0][0], 0, 0, 0);
      acc[0][1] = __builtin_amdgcn_mfma_f32_16x16x32_bf16(a0, b1, acc[0][1], 0, 0, 0);
      acc[1][0] = __builtin_amdgcn_mfma_f32_16x16x32_bf16(a1, b0, acc[1][0], 0, 0, 0);
      acc[1][1] = __builtin_amdgcn_mfma_f32_16x16x32_bf16(a1, b1, acc[1][1], 0, 0, 0);
    }
  }

  // C/D layout (m89-verified): col = lane&15, row = (lane>>4)*4 + reg
  const int cr = mo + fg * 4;  // + mi*16 + r  (block-local row)
  const int cc = no + fr;      // + ni*16      (block-local col)

  if (EPI == EPI_H1) {
    const float ts = tptr[0];
#pragma unroll
    for (int ni = 0; ni < 2; ++ni) {
      const int col = col0 + cc + ni * 16;
      const float add = v1[col] + ts * v2[col];
#pragma unroll
      for (int mi = 0; mi < 2; ++mi)
#pragma unroll
        for (int r = 0; r < 4; ++r) {
          const int row = row0 + cr + mi * 16 + r;
          bout[(size_t)row * Hsz + col] = f2bf(tanhf(acc[mi][ni][r] + add));
        }
    }
  } else if (EPI == EPI_AMAT) {
#pragma unroll
    for (int mi = 0; mi < 2; ++mi)
#pragma unroll
      for (int ni = 0; ni < 2; ++ni)
#pragma unroll
        for (int r = 0; r < 4; ++r) {
          const int row = row0 + cr + mi * 16 + r;
          const int col = col0 + cc + ni * 16;
          const float w2 = bf2f(aux[(size_t)row * Hsz + col]);  // W2bT[j][i] = W2[i][j]
          bout[(size_t)row * Hsz + col] = f2bf(w2 * acc[mi][ni][r]);
        }
  } else if (EPI == EPI_H2) {
#pragma unroll
    for (int ni = 0; ni < 2; ++ni) {
      const int col = col0 + cc + ni * 16;
      const float add = v1[col];
#pragma unroll
      for (int mi = 0; mi < 2; ++mi)
#pragma unroll
        for (int r = 0; r < 4; ++r) {
          const int row = row0 + cr + mi * 16 + r;
          bout[(size_t)row * Hsz + col] = f2bf(tanhf(acc[mi][ni][r] + add));
        }
    }
  } else if (EPI == EPI_DX) {
#pragma unroll
    for (int ni = 0; ni < 2; ++ni) {
      const int col = col0 + cc + ni * 16;
      const float add = v1[col];
#pragma unroll
      for (int mi = 0; mi < 2; ++mi)
#pragma unroll
        for (int r = 0; r < 4; ++r) {
          const int row = row0 + cr + mi * 16 + r;
          fout[(size_t)row * ldo + col] = acc[mi][ni][r] + add;
        }
    }
  } else {  // EPI_TRACE: s = sum_j U[b,j]*(1-h2[b,j]^2) ; atomicAdd per row
#pragma unroll
    for (int mi = 0; mi < 2; ++mi)
#pragma unroll
      for (int r = 0; r < 4; ++r) {
        const int row = row0 + cr + mi * 16 + r;
        float s = 0.f;
#pragma unroll
        for (int ni = 0; ni < 2; ++ni) {
          const int col = col0 + cc + ni * 16;
          const float h2 = bf2f(aux[(size_t)row * Hsz + col]);
          s += acc[mi][ni][r] * (1.0f - h2 * h2);
        }
        sred[cr + mi * 16 + r][(wid & 1) * 16 + fr] = s;
      }
    __syncthreads();
    if (t < 64) {
      float s = 0.f;
#pragma unroll
      for (int u = 0; u < 32; ++u) s += sred[t][u];
      atomicAdd(&fout[row0 + t], s);
    }
  }
}

// ---------------------------------------------------------------------------
// Launch.
// Algebra: ldj[b] = sum_{i,j} d1[b,i] * (W2 .* N)[i,j] * d2[b,j],
//   N = W1^T W3^T = (W3 W1)^T = M^T. AmatT[j][i] = W2[i][j]*M[j][i] is the
//   natural (coalesced) orientation of k2's M-tile AND the Bt layout k5 needs.
// ---------------------------------------------------------------------------
extern "C" void kernel_launch(void* const* d_in, const int* in_sizes, int n_in,
                              void* d_out, int out_size, void* d_ws, size_t ws_size,
                              hipStream_t stream) {
  const float* x  = (const float*)d_in[0];
  const float* t  = (const float*)d_in[1];
  const float* W1 = (const float*)d_in[4];
  const float* b1 = (const float*)d_in[5];
  const float* tW = (const float*)d_in[6];
  const float* W2 = (const float*)d_in[7];
  const float* b2 = (const float*)d_in[8];
  const float* W3 = (const float*)d_in[9];
  const float* b3 = (const float*)d_in[10];

  float* out = (float*)d_out;
  float* dx  = out;                      // [B,D]
  float* ldj = out + (size_t)Bsz * Dsz;  // [B], then reg [B]

  u16* w = (u16*)d_ws;
  u16* xb    = w;                    // [B][D]    262144
  u16* W1bT  = xb    + 262144;       // [H][D]    262144  (= W1^T)
  u16* W3b   = W1bT  + 262144;       // [H][D]    262144
  u16* W3bT  = W3b   + 262144;       // [D][H]    262144  (= W3^T)
  u16* W2bT  = W3bT  + 262144;       // [H][H]   1048576  (= W2^T)
  u16* AmatT = W2bT  + 1048576;      // [H][H]   1048576
  u16* H1b   = AmatT + 1048576;      // [B][H]   1048576
  u16* H2b   = H1b   + 1048576;      // [B][H]   1048576  (10.5 MB total)

  hipMemsetAsync(ldj, 0, 2 * Bsz * sizeof(float), stream);

  const dim3 blk(256);
  conv_cast<<<dim3(256), blk, 0, stream>>>(x,  xb,  Bsz * Dsz / 4);
  conv_cast<<<dim3(256), blk, 0, stream>>>(W3, W3b, Hsz * Dsz / 4);
  conv_tr<<<dim3(16, 4),  blk, 0, stream>>>(W1, W1bT, Dsz, Hsz);  // [D][H] -> [H][D]
  conv_tr<<<dim3(16, 16), blk, 0, stream>>>(W2, W2bT, Hsz, Hsz);  // [H][H] -> [H][H]
  conv_tr<<<dim3(4, 16),  blk, 0, stream>>>(W3, W3bT, Hsz, Dsz);  // [H][D] -> [D][H]

  // k1: H1b = tanh(x@W1 + b1 + ts*tW)            A=xb,  Bt=W1bT, K=D
  gemm_mfma<EPI_H1, false><<<dim3(16, 16), blk, 0, stream>>>(
      xb, W1bT, Dsz, Hsz, nullptr, H1b, nullptr, b1, tW, t);
  // k2: AmatT[j][i] = W2[i][j] * (W3@W1)[j][i]   A=W3b, Bt=W1bT, K=D
  gemm_mfma<EPI_AMAT, false><<<dim3(16, 16), blk, 0, stream>>>(
      W3b, W1bT, Dsz, Hsz, nullptr, AmatT, W2bT, nullptr, nullptr, nullptr);
  // k3: H2b = tanh(H1@W2 + b2)                   A=H1b, Bt=W2bT, K=H
  gemm_mfma<EPI_H2, false><<<dim3(16, 16), blk, 0, stream>>>(
      H1b, W2bT, Hsz, Hsz, nullptr, H2b, nullptr, b2, nullptr, nullptr);
  // k4: dx = H2@W3 + b3                          A=H2b, Bt=W3bT, K=H
  gemm_mfma<EPI_DX, false><<<dim3(4, 16), blk, 0, stream>>>(
      H2b, W3bT, Hsz, Dsz, dx, nullptr, nullptr, b3, nullptr, nullptr);
  // k5: ldj += rowsum( (d1@Amat) .* d2 )         A=d1(H1b,SQA), Bt=AmatT, K=H
  gemm_mfma<EPI_TRACE, true><<<dim3(16, 16), blk, 0, stream>>>(
      H1b, AmatT, Hsz, 0, ldj, nullptr, H2b, nullptr, nullptr, nullptr);
}

// Round 5
// 133.941 us; speedup vs baseline: 2.2859x; 1.1216x over previous
//
#include <hip/hip_runtime.h>
#include <math.h>

// Problem dims (fixed by setup_inputs): B=1024, D=256, H=1024
#define Bsz 1024
#define Dsz 256
#define Hsz 1024

typedef unsigned short u16;
typedef __bf16 bf16x8 __attribute__((ext_vector_type(8)));
typedef float  f32x4  __attribute__((ext_vector_type(4)));

__device__ __forceinline__ float bf2f(u16 u) {
  unsigned v = ((unsigned)u) << 16;
  return __builtin_bit_cast(float, v);
}
__device__ __forceinline__ u16 f2bf(float f) {
  unsigned u = __builtin_bit_cast(unsigned, f);
  u += 0x7FFFu + ((u >> 16) & 1u);  // round-to-nearest-even
  return (u16)(u >> 16);
}

// ---------------------------------------------------------------------------
// prep helpers
// ---------------------------------------------------------------------------
__device__ __forceinline__ void cast_chunk(const float* __restrict__ in,
                                           u16* __restrict__ out, int b, int t) {
  const int i = b * 256 + t;  // one float4 per thread
  const float4 v = reinterpret_cast<const float4*>(in)[i];
  ushort4 o;
  o.x = f2bf(v.x); o.y = f2bf(v.y); o.z = f2bf(v.z); o.w = f2bf(v.w);
  *reinterpret_cast<ushort4*>(&out[(size_t)i * 4]) = o;
}

// f32 [R][C] -> bf16 [C][R], one 64x64 tile at (r0, c0)
__device__ __forceinline__ void tr_tile(float (*tl)[65], const float* __restrict__ in,
                                        u16* __restrict__ out, int R, int C,
                                        int c0, int r0, int t) {
#pragma unroll
  for (int p = 0; p < 4; ++p) {
    const int r = p * 16 + (t >> 4);
    const int c = (t & 15) * 4;
    const float4 v = *reinterpret_cast<const float4*>(&in[(size_t)(r0 + r) * C + c0 + c]);
    tl[r][c] = v.x; tl[r][c + 1] = v.y; tl[r][c + 2] = v.z; tl[r][c + 3] = v.w;
  }
  __syncthreads();
#pragma unroll
  for (int p = 0; p < 4; ++p) {
    const int a = p * 16 + (t >> 4);   // out row (= in col)
    const int b4 = (t & 15) * 4;       // out col (= in row)
    ushort4 o;
    o.x = f2bf(tl[b4 + 0][a]); o.y = f2bf(tl[b4 + 1][a]);
    o.z = f2bf(tl[b4 + 2][a]); o.w = f2bf(tl[b4 + 3][a]);
    *reinterpret_cast<ushort4*>(&out[(size_t)(c0 + a) * R + r0 + b4]) = o;
  }
}

// ---------------------------------------------------------------------------
// prep: all casts/transposes + ldj/reg zeroing, one launch (896 blocks)
//  [0,256)   xb   = cast(x)        [B][D]
//  [256,512) W3b  = cast(W3)       [H][D]
//  [512,576) W1bT = tr(W1)         [H][D]   (64 tiles: 16x4)
//  [576,832) W2bT = tr(W2)         [H][H]   (256 tiles: 16x16)
//  [832,896) W3bT = tr(W3)         [D][H]   (64 tiles: 4x16)
//  block 0 also zeros ldj[1024]+reg[1024]
// ---------------------------------------------------------------------------
__global__ __launch_bounds__(256) void prep(const float* __restrict__ x,
                                            const float* __restrict__ W1,
                                            const float* __restrict__ W2,
                                            const float* __restrict__ W3,
                                            u16* __restrict__ xb,
                                            u16* __restrict__ W3b,
                                            u16* __restrict__ W1bT,
                                            u16* __restrict__ W2bT,
                                            u16* __restrict__ W3bT,
                                            float* __restrict__ ldj) {
  __shared__ float tl[64][65];
  const int b = blockIdx.x, t = threadIdx.x;
  if (b == 0) {
    for (int i = t; i < 2048; i += 256) ldj[i] = 0.0f;
  }
  if (b < 256) {
    cast_chunk(x, xb, b, t);
  } else if (b < 512) {
    cast_chunk(W3, W3b, b - 256, t);
  } else if (b < 576) {
    const int tb = b - 512;  // W1 [D][C=H] -> [H][D]
    tr_tile(tl, W1, W1bT, Dsz, Hsz, (tb & 15) * 64, (tb >> 4) * 64, t);
  } else if (b < 832) {
    const int tb = b - 576;  // W2 [H][H] -> [H][H]
    tr_tile(tl, W2, W2bT, Hsz, Hsz, (tb & 15) * 64, (tb >> 4) * 64, t);
  } else {
    const int tb = b - 832;  // W3 [H][C=D] -> [D][H]
    tr_tile(tl, W3, W3bT, Hsz, Dsz, (tb & 3) * 64, (tb >> 2) * 64, t);
  }
}

// ---------------------------------------------------------------------------
// MFMA GEMM body: C[64x64 tile] = A[M][K] * Bt[N][K]^T, bf16 in, f32 accum.
// 256 threads = 4 waves in 2x2; each wave a 32x32 quadrant (2x2 16x16 frags).
// BK=64, reg-prefetch. LDS rows padded to 72 bf16 (2-way bank max = free).
// SQA: transform A elems h -> 1-h*h while staging (d1 from H1b, no buffer).
// ---------------------------------------------------------------------------
enum { EPI_H1 = 0, EPI_AMAT = 1, EPI_H2 = 2, EPI_DX = 3, EPI_TRACE = 4 };
constexpr int LS = 72;

template <int EPI, bool SQA>
__device__ __forceinline__ void gemm_body(
    int row0, int col0,
    u16* __restrict__ As, u16* __restrict__ Bs, float (*sred)[33],
    const u16* __restrict__ A, const u16* __restrict__ Bt,
    int K, int ldo,
    float* __restrict__ fout, u16* __restrict__ bout,
    const u16* __restrict__ aux,
    const float* __restrict__ v1, const float* __restrict__ v2,
    const float* __restrict__ tptr) {
  const int t = threadIdx.x;
  const int lane = t & 63, wid = t >> 6;

  const int sm = t >> 2, sq = t & 3;
  const size_t a_base = (size_t)(row0 + sm) * K + sq * 8;
  const size_t b_base = (size_t)(col0 + sm) * K + sq * 8;

  uint4 ar[2], br[2];
  auto load_regs = [&](int k0) {
    ar[0] = *reinterpret_cast<const uint4*>(&A[a_base + k0]);
    ar[1] = *reinterpret_cast<const uint4*>(&A[a_base + k0 + 32]);
    br[0] = *reinterpret_cast<const uint4*>(&Bt[b_base + k0]);
    br[1] = *reinterpret_cast<const uint4*>(&Bt[b_base + k0 + 32]);
  };
  auto sq_tr = [&](uint4 v) -> uint4 {
    u16* p = reinterpret_cast<u16*>(&v);
    uint4 o; u16* po = reinterpret_cast<u16*>(&o);
#pragma unroll
    for (int i = 0; i < 8; ++i) { const float h = bf2f(p[i]); po[i] = f2bf(1.0f - h * h); }
    return o;
  };
  auto store_lds = [&]() {
    const int ab = sm * LS + sq * 8;
#pragma unroll
    for (int c = 0; c < 2; ++c) {
      const uint4 av = SQA ? sq_tr(ar[c]) : ar[c];
      *reinterpret_cast<uint4*>(&As[ab + c * 32]) = av;
      *reinterpret_cast<uint4*>(&Bs[ab + c * 32]) = br[c];
    }
  };

  f32x4 acc[2][2] = {};
  const int mo = (wid >> 1) * 32, no = (wid & 1) * 32;
  const int fr = lane & 15, fg = lane >> 4;

  const int NK = K >> 6;
  load_regs(0);
  for (int it = 0; it < NK; ++it) {
    __syncthreads();          // previous compute done; LDS free
    store_lds();
    if (it + 1 < NK) load_regs((it + 1) << 6);
    __syncthreads();          // tile visible
#pragma unroll
    for (int ks = 0; ks < 64; ks += 32) {
      union { uint4 u; bf16x8 b; } cv;
      cv.u = *reinterpret_cast<const uint4*>(&As[(mo + fr) * LS + ks + fg * 8]);
      const bf16x8 a0 = cv.b;
      cv.u = *reinterpret_cast<const uint4*>(&As[(mo + 16 + fr) * LS + ks + fg * 8]);
      const bf16x8 a1 = cv.b;
      cv.u = *reinterpret_cast<const uint4*>(&Bs[(no + fr) * LS + ks + fg * 8]);
      const bf16x8 b0 = cv.b;
      cv.u = *reinterpret_cast<const uint4*>(&Bs[(no + 16 + fr) * LS + ks + fg * 8]);
      const bf16x8 b1 = cv.b;
      acc[0][0] = __builtin_amdgcn_mfma_f32_16x16x32_bf16(a0, b0, acc[0][0], 0, 0, 0);
      acc[0][1] = __builtin_amdgcn_mfma_f32_16x16x32_bf16(a0, b1, acc[0][1], 0, 0, 0);
      acc[1][0] = __builtin_amdgcn_mfma_f32_16x16x32_bf16(a1, b0, acc[1][0], 0, 0, 0);
      acc[1][1] = __builtin_amdgcn_mfma_f32_16x16x32_bf16(a1, b1, acc[1][1], 0, 0, 0);
    }
  }

  // C/D layout (m89-verified): col = lane&15, row = (lane>>4)*4 + reg
  const int cr = mo + fg * 4;  // + mi*16 + r  (block-local row)
  const int cc = no + fr;      // + ni*16      (block-local col)

  if (EPI == EPI_H1) {
    const float ts = tptr[0];
#pragma unroll
    for (int ni = 0; ni < 2; ++ni) {
      const int col = col0 + cc + ni * 16;
      const float add = v1[col] + ts * v2[col];
#pragma unroll
      for (int mi = 0; mi < 2; ++mi)
#pragma unroll
        for (int r = 0; r < 4; ++r) {
          const int row = row0 + cr + mi * 16 + r;
          bout[(size_t)row * Hsz + col] = f2bf(tanhf(acc[mi][ni][r] + add));
        }
    }
  } else if (EPI == EPI_AMAT) {
#pragma unroll
    for (int mi = 0; mi < 2; ++mi)
#pragma unroll
      for (int ni = 0; ni < 2; ++ni)
#pragma unroll
        for (int r = 0; r < 4; ++r) {
          const int row = row0 + cr + mi * 16 + r;
          const int col = col0 + cc + ni * 16;
          const float w2 = bf2f(aux[(size_t)row * Hsz + col]);  // W2bT[j][i] = W2[i][j]
          bout[(size_t)row * Hsz + col] = f2bf(w2 * acc[mi][ni][r]);
        }
  } else if (EPI == EPI_H2) {
#pragma unroll
    for (int ni = 0; ni < 2; ++ni) {
      const int col = col0 + cc + ni * 16;
      const float add = v1[col];
#pragma unroll
      for (int mi = 0; mi < 2; ++mi)
#pragma unroll
        for (int r = 0; r < 4; ++r) {
          const int row = row0 + cr + mi * 16 + r;
          bout[(size_t)row * Hsz + col] = f2bf(tanhf(acc[mi][ni][r] + add));
        }
    }
  } else if (EPI == EPI_DX) {
#pragma unroll
    for (int ni = 0; ni < 2; ++ni) {
      const int col = col0 + cc + ni * 16;
      const float add = v1[col];
#pragma unroll
      for (int mi = 0; mi < 2; ++mi)
#pragma unroll
        for (int r = 0; r < 4; ++r) {
          const int row = row0 + cr + mi * 16 + r;
          fout[(size_t)row * ldo + col] = acc[mi][ni][r] + add;
        }
    }
  } else {  // EPI_TRACE: s = sum_j U[b,j]*(1-h2[b,j]^2) ; atomicAdd per row
#pragma unroll
    for (int mi = 0; mi < 2; ++mi)
#pragma unroll
      for (int r = 0; r < 4; ++r) {
        const int row = row0 + cr + mi * 16 + r;
        float s = 0.f;
#pragma unroll
        for (int ni = 0; ni < 2; ++ni) {
          const int col = col0 + cc + ni * 16;
          const float h2 = bf2f(aux[(size_t)row * Hsz + col]);
          s += acc[mi][ni][r] * (1.0f - h2 * h2);
        }
        sred[cr + mi * 16 + r][(wid & 1) * 16 + fr] = s;
      }
    __syncthreads();
    if (t < 64) {
      float s = 0.f;
#pragma unroll
      for (int u = 0; u < 32; ++u) s += sred[t][u];
      atomicAdd(&fout[row0 + t], s);
    }
  }
}

// ---------------------------------------------------------------------------
// Phase B (512 blocks): k1 H1b=tanh(x@W1+b1+ts*tW)  +  k2 AmatT=(W3@W1)ᵀ.*W2ᵀ
// ---------------------------------------------------------------------------
__global__ __launch_bounds__(256) void phaseB(const u16* __restrict__ xb,
                                              const u16* __restrict__ W1bT,
                                              const u16* __restrict__ W3b,
                                              const u16* __restrict__ W2bT,
                                              u16* __restrict__ H1b,
                                              u16* __restrict__ AmatT,
                                              const float* __restrict__ b1,
                                              const float* __restrict__ tW,
                                              const float* __restrict__ t) {
  __shared__ u16 As[64 * LS];
  __shared__ u16 Bs[64 * LS];
  const int b = blockIdx.x;
  if (b < 256) {
    gemm_body<EPI_H1, false>((b >> 4) * 64, (b & 15) * 64, As, Bs, nullptr,
                             xb, W1bT, Dsz, Hsz, nullptr, H1b, nullptr, b1, tW, t);
  } else {
    const int c = b - 256;
    gemm_body<EPI_AMAT, false>((c >> 4) * 64, (c & 15) * 64, As, Bs, nullptr,
                               W3b, W1bT, Dsz, Hsz, nullptr, AmatT, W2bT,
                               nullptr, nullptr, nullptr);
  }
}

// ---------------------------------------------------------------------------
// Phase C (256 blocks): k3 H2b = tanh(H1@W2 + b2), K=H
// ---------------------------------------------------------------------------
__global__ __launch_bounds__(256) void phaseC(const u16* __restrict__ H1b,
                                              const u16* __restrict__ W2bT,
                                              u16* __restrict__ H2b,
                                              const float* __restrict__ b2) {
  __shared__ u16 As[64 * LS];
  __shared__ u16 Bs[64 * LS];
  const int b = blockIdx.x;
  gemm_body<EPI_H2, false>((b >> 4) * 64, (b & 15) * 64, As, Bs, nullptr,
                           H1b, W2bT, Hsz, Hsz, nullptr, H2b, nullptr, b2,
                           nullptr, nullptr);
}

// ---------------------------------------------------------------------------
// Phase D (320 blocks): k5 trace (256, heavy, first) + k4 dx (64)
// ---------------------------------------------------------------------------
__global__ __launch_bounds__(256) void phaseD(const u16* __restrict__ H1b,
                                              const u16* __restrict__ AmatT,
                                              const u16* __restrict__ H2b,
                                              const u16* __restrict__ W3bT,
                                              float* __restrict__ ldj,
                                              float* __restrict__ dx,
                                              const float* __restrict__ b3) {
  __shared__ u16 As[64 * LS];
  __shared__ u16 Bs[64 * LS];
  __shared__ float sred[64][33];
  const int b = blockIdx.x;
  if (b < 256) {
    gemm_body<EPI_TRACE, true>((b >> 4) * 64, (b & 15) * 64, As, Bs, sred,
                               H1b, AmatT, Hsz, 0, ldj, nullptr, H2b,
                               nullptr, nullptr, nullptr);
  } else {
    const int c = b - 256;
    gemm_body<EPI_DX, false>((c >> 2) * 64, (c & 3) * 64, As, Bs, nullptr,
                             H2b, W3bT, Hsz, Dsz, dx, nullptr, nullptr, b3,
                             nullptr, nullptr);
  }
}

// ---------------------------------------------------------------------------
// Launch: 4 dispatches.
// Algebra: ldj[b] = sum_{i,j} d1[b,i]*(W2.*N)[i,j]*d2[b,j], N = (W3@W1)ᵀ.
// AmatT[j][i] = W2[i][j]*(W3@W1)[j][i] is k2's natural tile orientation AND
// the Bt layout k5 consumes.
// ---------------------------------------------------------------------------
extern "C" void kernel_launch(void* const* d_in, const int* in_sizes, int n_in,
                              void* d_out, int out_size, void* d_ws, size_t ws_size,
                              hipStream_t stream) {
  const float* x  = (const float*)d_in[0];
  const float* t  = (const float*)d_in[1];
  const float* W1 = (const float*)d_in[4];
  const float* b1 = (const float*)d_in[5];
  const float* tW = (const float*)d_in[6];
  const float* W2 = (const float*)d_in[7];
  const float* b2 = (const float*)d_in[8];
  const float* W3 = (const float*)d_in[9];
  const float* b3 = (const float*)d_in[10];

  float* out = (float*)d_out;
  float* dx  = out;                      // [B,D]
  float* ldj = out + (size_t)Bsz * Dsz;  // [B], then reg [B]

  u16* w = (u16*)d_ws;
  u16* xb    = w;                    // [B][D]    262144
  u16* W1bT  = xb    + 262144;       // [H][D]    262144  (= W1^T)
  u16* W3b   = W1bT  + 262144;       // [H][D]    262144
  u16* W3bT  = W3b   + 262144;       // [D][H]    262144  (= W3^T)
  u16* W2bT  = W3bT  + 262144;       // [H][H]   1048576  (= W2^T)
  u16* AmatT = W2bT  + 1048576;      // [H][H]   1048576
  u16* H1b   = AmatT + 1048576;      // [B][H]   1048576
  u16* H2b   = H1b   + 1048576;      // [B][H]   1048576  (10.5 MB total)

  const dim3 blk(256);
  prep  <<<dim3(896), blk, 0, stream>>>(x, W1, W2, W3, xb, W3b, W1bT, W2bT, W3bT, ldj);
  phaseB<<<dim3(512), blk, 0, stream>>>(xb, W1bT, W3b, W2bT, H1b, AmatT, b1, tW, t);
  phaseC<<<dim3(256), blk, 0, stream>>>(H1b, W2bT, H2b, b2);
  phaseD<<<dim3(320), blk, 0, stream>>>(H1b, AmatT, H2b, W3bT, ldj, dx, b3);
}